// Round 13
// baseline (111.086 us; speedup 1.0000x reference)
//
#include <hip/hip_runtime.h>

#define NBK 10
#define KK  9
#define SC_AGENT __HIP_MEMORY_SCOPE_AGENT

constexpr int Bv  = 4;
constexpr int Vv  = 5023;
constexpr int TOT = Bv * Vv;   // 20092
constexpr int NBLK_F = 1256;   // fused grid: 16 vertex-groups per 256-thr block
constexpr int NBARS  = 5;

// interleaved row strides: RS32: h 0..15, ux 16..24;  RS48: h 0..31, ux 32..40

// ---------------------------------------------------------------------------
// Relaxed split-counter device barrier (functionally verified r5: no fences,
// no L2 maintenance). Per-wave vmcnt(0) drain happens at the compiler-emitted
// s_waitcnt before s_barrier in __syncthreads(); bypass stores are therefore
// at L3 before the arrival add.
// ---------------------------------------------------------------------------
struct Bar {
    int lo[16 * 32];
    int hi;   int p1[31];
    int flag; int p2[31];
};

__device__ __forceinline__ void bar_sync(Bar* bar, int bid, int tid)
{
    __syncthreads();
    if (tid == 0) {
        const int g    = bid & 15;
        const int need = (NBLK_F >> 4) + ((g < (NBLK_F & 15)) ? 1 : 0);
        const int old = __hip_atomic_fetch_add(&bar->lo[g * 32], 1,
                                               __ATOMIC_RELAXED, SC_AGENT);
        if (old == need - 1) {
            const int oh = __hip_atomic_fetch_add(&bar->hi, 1,
                                                  __ATOMIC_RELAXED, SC_AGENT);
            if (oh == 15)
                __hip_atomic_store(&bar->flag, 1, __ATOMIC_RELAXED, SC_AGENT);
        }
        while (__hip_atomic_load(&bar->flag, __ATOMIC_RELAXED, SC_AGENT) == 0)
            __builtin_amdgcn_s_sleep(2);
    }
    __syncthreads();
}

// Inter-layer h/ux stores: L2-bypass (coherent at L3, never dirties any L2).
__device__ __forceinline__ void sto(float* p, float v)
{
    __hip_atomic_store(p, v, __ATOMIC_RELAXED, SC_AGENT);
}

// ---------------------------------------------------------------------------
// 16-lane merge-tree reduce (verified r3-r12).
// ---------------------------------------------------------------------------
__device__ __forceinline__ float merge16(float* a, int t)
{
#pragma unroll
    for (int j = 0; j < 8; j++) {
        float send = (t & 8) ? a[j] : a[j + 8];
        float keep = (t & 8) ? a[j + 8] : a[j];
        a[j] = keep + __shfl_xor(send, 8, 16);
    }
#pragma unroll
    for (int j = 0; j < 4; j++) {
        float send = (t & 4) ? a[j] : a[j + 4];
        float keep = (t & 4) ? a[j + 4] : a[j];
        a[j] = keep + __shfl_xor(send, 4, 16);
    }
#pragma unroll
    for (int j = 0; j < 2; j++) {
        float send = (t & 2) ? a[j] : a[j + 2];
        float keep = (t & 2) ? a[j + 2] : a[j];
        a[j] = keep + __shfl_xor(send, 2, 16);
    }
    {
        float send = (t & 1) ? a[0] : a[1];
        float keep = (t & 1) ? a[1] : a[0];
        a[0] = keep + __shfl_xor(send, 1, 16);
    }
    return a[0];
}

// ---------------------------------------------------------------------------
// Layer 0 body (enc fold, verified r10/r12 math). Stage-first. STO=bypass.
// ---------------------------------------------------------------------------
template<bool STO>
__device__ __forceinline__ void layer0_body(
    int tid, int g, int t, bool act, int b, int v, int vv,
    const int* nb, float rec,
    const float* __restrict__ x, const float* __restrict__ Win,
    const float* __restrict__ u0, const float* __restrict__ W,
    const float* __restrict__ bvec, const float* __restrict__ cvec,
    const float* __restrict__ unx, float* __restrict__ hux_out,
    float* s_w)
{
    constexpr int COUTP = 20;
    {
        constexpr int NF4 = 16 * KK * 16 / 4;   // 576
        constexpr int KC4 = KK * 16 / 4;        // 36
        const float4* W4 = reinterpret_cast<const float4*>(W);
        for (int i = tid; i < NF4; i += 256) {
            const int c   = i / KC4;
            const int rem = i - c * KC4;
            const int k   = rem >> 2;
            const int o4  = rem & 3;
            *reinterpret_cast<float4*>(&s_w[(k * 16 + c) * COUTP + o4 * 4]) = W4[i];
        }
    }
    __syncthreads();

    const float* xB = x + (size_t)b * Vv * 3;
    const float w0 = Win[t], w1 = Win[16 + t], w2 = Win[32 + t];
    float hn0[NBK];
#pragma unroll
    for (int n = 0; n < NBK; n++) {
        const int a = act ? nb[n] : 0;
        float x0 = 0.f, x1 = 0.f, x2 = 0.f;
        if (a) {
            const float* xr = &xB[(size_t)(a - 1) * 3];
            x0 = xr[0]; x1 = xr[1]; x2 = xr[2];
        }
        hn0[n] = fmaxf(x0 * w0 + x1 * w1 + x2 * w2, 0.0f);
    }

    float q[KK] = {};
    if (act && t < NBK) {
        const float* xo = &xB[(size_t)v * 3];
        const float xo0 = xo[0], xo1 = xo[1], xo2 = xo[2];
        const int a = nb[t];
        float xn0 = 0.f, xn1 = 0.f, xn2 = 0.f;
        if (a) {
            const float* xr = &xB[(size_t)(a - 1) * 3];
            xn0 = xr[0]; xn1 = xr[1]; xn2 = xr[2];
        }
        float hs[16];
#pragma unroll
        for (int c = 0; c < 16; c++) {
            const float ho = fmaxf(xo0 * Win[c] + xo1 * Win[16 + c] + xo2 * Win[32 + c], 0.0f);
            const float hn = fmaxf(xn0 * Win[c] + xn1 * Win[16 + c] + xn2 * Win[32 + c], 0.0f);
            hs[c] = ho + hn;
        }
        float lg[KK];
#pragma unroll
        for (int k = 0; k < KK; k++) {
            float s = cvec[k];
#pragma unroll
            for (int c = 0; c < 16; c++) s = fmaf(hs[c], u0[c * KK + k], s);
            lg[k] = s;
        }
        float m = lg[0];
#pragma unroll
        for (int k = 1; k < KK; k++) m = fmaxf(m, lg[k]);
        float sum = 0.0f;
#pragma unroll
        for (int k = 0; k < KK; k++) { q[k] = __expf(lg[k] - m); sum += q[k]; }
        const float r = 1.0f / sum;
#pragma unroll
        for (int k = 0; k < KK; k++) q[k] *= r;
    }

    float g0[KK];
#pragma unroll
    for (int k = 0; k < KK; k++) g0[k] = 0.0f;
#pragma unroll
    for (int n = 0; n < NBK; n++) {
#pragma unroll
        for (int k = 0; k < KK; k++) {
            const float qnk = __shfl(q[k], n, 16);
            g0[k] = fmaf(qnk, hn0[n], g0[k]);
        }
    }

    float acc[16] = {};
#pragma unroll
    for (int k = 0; k < KK; k++) {
        const float g0k = g0[k];
        const float* wr = &s_w[(k * 16 + t) * COUTP];
#pragma unroll
        for (int o4 = 0; o4 < 4; o4++) {
            const float4 w = *reinterpret_cast<const float4*>(&wr[4 * o4]);
            acc[4 * o4 + 0] = fmaf(g0k, w.x, acc[4 * o4 + 0]);
            acc[4 * o4 + 1] = fmaf(g0k, w.y, acc[4 * o4 + 1]);
            acc[4 * o4 + 2] = fmaf(g0k, w.z, acc[4 * o4 + 2]);
            acc[4 * o4 + 3] = fmaf(g0k, w.w, acc[4 * o4 + 3]);
        }
    }

    const float o0 = merge16(acc, t);
    const float h0v = fmaxf(fmaf(o0, rec, bvec[t]), 0.0f);
    if (act) {
        if (STO) sto(&hux_out[(size_t)vv * 32 + t], h0v);
        else     hux_out[(size_t)vv * 32 + t] = h0v;
    }

    float uxv = 0.0f;
#pragma unroll
    for (int o = 0; o < 16; o++) {
        const float hb = __shfl(h0v, o, 16);
        if (t < KK) uxv = fmaf(hb, unx[o * KK + t], uxv);
    }
    if (act && t < KK) {
        if (STO) sto(&hux_out[(size_t)vv * 32 + 16 + t], uxv);
        else     hux_out[(size_t)vv * 32 + 16 + t] = uxv;
    }
}

// ---------------------------------------------------------------------------
// NLayer body (verified r12 code; gathers-early; NSTRIDE = block threads).
// Loads: NORMAL cached. Stores: bypass if STO.
// ---------------------------------------------------------------------------
template<int CIN, int COUT, bool LAST, int RSI, int RSO, bool STO, int NSTRIDE>
__device__ __forceinline__ void nlayer_body(
    int tid, int g, int t, bool act, int b, int v, int vv,
    const int* nb, float rec,
    const float* __restrict__ hux_in,
    const float* __restrict__ W, const float* __restrict__ bvec,
    const float* __restrict__ cvec, const float* __restrict__ unx,
    float* __restrict__ hux_out, float* __restrict__ dout,
    float* s_w, float (*s_q)[NBK][12])
{
    constexpr int COUTP = (COUT == 32) ? 36 : ((COUT == 16) ? 20 : 4);
    const float* inB = hux_in + (size_t)b * Vv * RSI;

    // --- early: register gather of neighbor h (owned channel(s)) ---
    float hn0[NBK], hn1[NBK];
#pragma unroll
    for (int n = 0; n < NBK; n++) {
        const int a = act ? nb[n] : 0;
        const float* r = &inB[(size_t)(a - 1) * RSI];
        hn0[n] = a ? r[t] : 0.0f;
        if constexpr (CIN == 32) hn1[n] = a ? r[t + 16] : 0.0f;
        else                     hn1[n] = 0.0f;
    }

    // --- early: own + neighbor ux (lane t<10) ---
    float4 s0 = make_float4(0.f, 0.f, 0.f, 0.f), s1 = s0, n0 = s0, n1 = s0;
    float  s8 = 0.f, n8 = 0.f;
    if (act && t < NBK) {
        const float* su = &inB[(size_t)v * RSI + CIN];
        s0 = *reinterpret_cast<const float4*>(su);
        s1 = *reinterpret_cast<const float4*>(su + 4);
        s8 = su[8];
        const int a = nb[t];
        if (a) {
            const float* nu = &inB[(size_t)(a - 1) * RSI + CIN];
            n0 = *reinterpret_cast<const float4*>(nu);
            n1 = *reinterpret_cast<const float4*>(nu + 4);
            n8 = nu[8];
        }
    }

    // --- stage W -> LDS [k][c][o] padded ---
    if constexpr (!LAST) {
        constexpr int NF4 = CIN * KK * COUT / 4;
        constexpr int KC4 = KK * COUT / 4;
        constexpr int C4  = COUT / 4;
        const float4* W4 = reinterpret_cast<const float4*>(W);
        for (int i = tid; i < NF4; i += NSTRIDE) {
            const int c   = i / KC4;
            const int rem = i - c * KC4;
            const int k   = rem / C4;
            const int o4  = rem - k * C4;
            *reinterpret_cast<float4*>(&s_w[(k * CIN + c) * COUTP + o4 * 4]) = W4[i];
        }
    } else {
        for (int i = tid; i < CIN * KK * 3; i += NSTRIDE) {
            const int c   = i / (KK * 3);
            const int rem = i - c * (KK * 3);
            const int k   = rem / 3;
            const int o   = rem - k * 3;
            s_w[(k * CIN + c) * COUTP + o] = W[i];
        }
    }
    __syncthreads();

    // --- softmax (lane t<10) -> wave-private s_q ---
    if (act && t < NBK) {
        float lg[KK] = { s0.x + n0.x + cvec[0], s0.y + n0.y + cvec[1],
                         s0.z + n0.z + cvec[2], s0.w + n0.w + cvec[3],
                         s1.x + n1.x + cvec[4], s1.y + n1.y + cvec[5],
                         s1.z + n1.z + cvec[6], s1.w + n1.w + cvec[7],
                         s8 + n8 + cvec[8] };
        float m = lg[0];
#pragma unroll
        for (int k = 1; k < KK; k++) m = fmaxf(m, lg[k]);
        float e[KK], sum = 0.0f;
#pragma unroll
        for (int k = 0; k < KK; k++) { e[k] = __expf(lg[k] - m); sum += e[k]; }
        const float r = 1.0f / sum;
        *reinterpret_cast<float4*>(&s_q[g][t][0]) =
            make_float4(e[0] * r, e[1] * r, e[2] * r, e[3] * r);
        *reinterpret_cast<float4*>(&s_q[g][t][4]) =
            make_float4(e[4] * r, e[5] * r, e[6] * r, e[7] * r);
        s_q[g][t][8] = e[8] * r;
    }
    // wave-local LDS RAW: lgkmcnt orders write->read within the wave.

    // --- G-phase ---
    float g0[KK], g1[KK];
#pragma unroll
    for (int k = 0; k < KK; k++) { g0[k] = 0.0f; g1[k] = 0.0f; }
#pragma unroll
    for (int n = 0; n < NBK; n++) {
        const float4 qa = *reinterpret_cast<const float4*>(&s_q[g][n][0]);
        const float4 qb = *reinterpret_cast<const float4*>(&s_q[g][n][4]);
        const float  q8 = s_q[g][n][8];
        const float h0 = hn0[n];
        g0[0] = fmaf(qa.x, h0, g0[0]); g0[1] = fmaf(qa.y, h0, g0[1]);
        g0[2] = fmaf(qa.z, h0, g0[2]); g0[3] = fmaf(qa.w, h0, g0[3]);
        g0[4] = fmaf(qb.x, h0, g0[4]); g0[5] = fmaf(qb.y, h0, g0[5]);
        g0[6] = fmaf(qb.z, h0, g0[6]); g0[7] = fmaf(qb.w, h0, g0[7]);
        g0[8] = fmaf(q8,   h0, g0[8]);
        if constexpr (CIN == 32) {
            const float h1 = hn1[n];
            g1[0] = fmaf(qa.x, h1, g1[0]); g1[1] = fmaf(qa.y, h1, g1[1]);
            g1[2] = fmaf(qa.z, h1, g1[2]); g1[3] = fmaf(qa.w, h1, g1[3]);
            g1[4] = fmaf(qb.x, h1, g1[4]); g1[5] = fmaf(qb.y, h1, g1[5]);
            g1[6] = fmaf(qb.z, h1, g1[6]); g1[7] = fmaf(qb.w, h1, g1[7]);
            g1[8] = fmaf(q8,   h1, g1[8]);
        }
    }

    if constexpr (!LAST) {
        float acc[COUT] = {};
#pragma unroll
        for (int k = 0; k < KK; k++) {
            const float g0k = g0[k];
            const float* wr = &s_w[(k * CIN + t) * COUTP];
#pragma unroll
            for (int o4 = 0; o4 < COUT / 4; o4++) {
                const float4 w = *reinterpret_cast<const float4*>(&wr[4 * o4]);
                acc[4 * o4 + 0] = fmaf(g0k, w.x, acc[4 * o4 + 0]);
                acc[4 * o4 + 1] = fmaf(g0k, w.y, acc[4 * o4 + 1]);
                acc[4 * o4 + 2] = fmaf(g0k, w.z, acc[4 * o4 + 2]);
                acc[4 * o4 + 3] = fmaf(g0k, w.w, acc[4 * o4 + 3]);
            }
            if constexpr (CIN == 32) {
                const float g1k = g1[k];
                const float* wr2 = &s_w[(k * CIN + t + 16) * COUTP];
#pragma unroll
                for (int o4 = 0; o4 < COUT / 4; o4++) {
                    const float4 w = *reinterpret_cast<const float4*>(&wr2[4 * o4]);
                    acc[4 * o4 + 0] = fmaf(g1k, w.x, acc[4 * o4 + 0]);
                    acc[4 * o4 + 1] = fmaf(g1k, w.y, acc[4 * o4 + 1]);
                    acc[4 * o4 + 2] = fmaf(g1k, w.z, acc[4 * o4 + 2]);
                    acc[4 * o4 + 3] = fmaf(g1k, w.w, acc[4 * o4 + 3]);
                }
            }
        }

        const float o0 = merge16(acc, t);
        const float h0v = fmaxf(fmaf(o0, rec, bvec[t]), 0.0f);
        float* row = &hux_out[(size_t)vv * RSO];
        if (act) { if (STO) sto(&row[t], h0v); else row[t] = h0v; }
        float h1v = 0.0f;
        if constexpr (COUT == 32) {
            const float o1 = merge16(acc + 16, t);
            h1v = fmaxf(fmaf(o1, rec, bvec[t + 16]), 0.0f);
            if (act) { if (STO) sto(&row[16 + t], h1v); else row[16 + t] = h1v; }
        }

        float uxv = 0.0f;
#pragma unroll
        for (int o = 0; o < 16; o++) {
            const float hb = __shfl(h0v, o, 16);
            if (t < KK) uxv = fmaf(hb, unx[o * KK + t], uxv);
        }
        if constexpr (COUT == 32) {
#pragma unroll
            for (int o = 0; o < 16; o++) {
                const float hb = __shfl(h1v, o, 16);
                if (t < KK) uxv = fmaf(hb, unx[(o + 16) * KK + t], uxv);
            }
        }
        if (act && t < KK) {
            if (STO) sto(&row[COUT + t], uxv);
            else     row[COUT + t] = uxv;
        }
    } else {
        float acc[3] = {};
#pragma unroll
        for (int k = 0; k < KK; k++) {
            const float4 w = *reinterpret_cast<const float4*>(&s_w[(k * CIN + t) * COUTP]);
            acc[0] = fmaf(g0[k], w.x, acc[0]);
            acc[1] = fmaf(g0[k], w.y, acc[1]);
            acc[2] = fmaf(g0[k], w.z, acc[2]);
        }
#pragma unroll
        for (int o = 0; o < 3; o++) {
            acc[o] += __shfl_xor(acc[o], 1, 16);
            acc[o] += __shfl_xor(acc[o], 2, 16);
            acc[o] += __shfl_xor(acc[o], 4, 16);
            acc[o] += __shfl_xor(acc[o], 8, 16);
        }
        float hnew[3];
#pragma unroll
        for (int o = 0; o < 3; o++)
            hnew[o] = fmaxf(fmaf(acc[o], rec, bvec[o]), 0.0f);
        if (act && t < 3) {
            float s = 0.0f;
#pragma unroll
            for (int j = 0; j < 3; j++)
                s = fmaf(hnew[j], unx[j * 3 + t], s);
            dout[(size_t)vv * 3 + t] = s;   // final output: normal store
        }
    }
}

// ---------------------------------------------------------------------------
struct KArgs {
    const float* x; const int* adj; const float* Win; const float* Wout;
    const float* W[6]; const float* bv[6]; const float* uv[6]; const float* cv[6];
    Bar* bars;
    float* B1; float* B2; float* B3; float* B4; float* B5;
    float* out;
};

__global__ __launch_bounds__(256, 5) void fused_kernel(KArgs A)
{
    __shared__ __align__(16) float s_w[5760];            // max 9*32*20
    __shared__ __align__(16) float s_q[16][NBK][12];

    const int tid = threadIdx.x;
    const int bid = blockIdx.x;
    const int g = tid >> 4;
    const int t = tid & 15;
    const int vv = bid * 16 + g;
    const bool act = vv < TOT;
    int b = 0, v = 0;
    if (act) { b = vv / Vv; v = vv - b * Vv; }

    // adjacency + recip loaded ONCE, reused for all 6 layers
    int nb[NBK];
    if (act) {
        const int2* arow = reinterpret_cast<const int2*>(&A.adj[v * NBK]);
#pragma unroll
        for (int j = 0; j < 5; j++) { int2 p = arow[j]; nb[2 * j] = p.x; nb[2 * j + 1] = p.y; }
    } else {
#pragma unroll
        for (int n = 0; n < NBK; n++) nb[n] = 0;
    }
    int cnt = 0;
#pragma unroll
    for (int n = 0; n < NBK; n++) cnt += (nb[n] != 0) ? 1 : 0;
    const float rec = cnt ? (1.0f / (float)cnt) : 0.0f;

    layer0_body<true>(tid, g, t, act, b, v, vv, nb, rec,
        A.x, A.Win, A.uv[0], A.W[0], A.bv[0], A.cv[0], A.uv[1], A.B1, s_w);
    bar_sync(&A.bars[0], bid, tid);
    nlayer_body<16, 16, false, 32, 32, true, 256>(tid, g, t, act, b, v, vv, nb, rec,
        A.B1, A.W[1], A.bv[1], A.cv[1], A.uv[2], A.B2, nullptr, s_w, s_q);
    bar_sync(&A.bars[1], bid, tid);
    nlayer_body<16, 32, false, 32, 48, true, 256>(tid, g, t, act, b, v, vv, nb, rec,
        A.B2, A.W[2], A.bv[2], A.cv[2], A.uv[3], A.B3, nullptr, s_w, s_q);
    bar_sync(&A.bars[2], bid, tid);
    nlayer_body<32, 16, false, 48, 32, true, 256>(tid, g, t, act, b, v, vv, nb, rec,
        A.B3, A.W[3], A.bv[3], A.cv[3], A.uv[4], A.B4, nullptr, s_w, s_q);
    bar_sync(&A.bars[3], bid, tid);
    nlayer_body<16, 16, false, 32, 32, true, 256>(tid, g, t, act, b, v, vv, nb, rec,
        A.B4, A.W[4], A.bv[4], A.cv[4], A.uv[5], A.B5, nullptr, s_w, s_q);
    bar_sync(&A.bars[4], bid, tid);
    nlayer_body<16, 3, true, 32, 32, true, 256>(tid, g, t, act, b, v, vv, nb, rec,
        A.B5, A.W[5], A.bv[5], A.cv[5], A.Wout, nullptr, A.out, s_w, s_q);
}

// ===========================================================================
// Host-side fallback: verified r12 six-dispatch path.
// ===========================================================================
__global__ __launch_bounds__(256, 4) void enc_l0_kernel(
    const float* __restrict__ x, const int* __restrict__ adj,
    const float* __restrict__ Win, const float* __restrict__ u0,
    const float* __restrict__ W, const float* __restrict__ bvec,
    const float* __restrict__ cvec, const float* __restrict__ unx,
    float* __restrict__ hux_out)
{
    __shared__ __align__(16) float s_w[KK * 16 * 20];
    const int tid = threadIdx.x;
    const int g = tid >> 4;
    const int t = tid & 15;
    const int vv = blockIdx.x * 16 + g;
    const bool act = vv < TOT;
    int b = 0, v = 0;
    if (act) { b = vv / Vv; v = vv - b * Vv; }
    int nb[NBK];
    if (act) {
        const int2* arow = reinterpret_cast<const int2*>(&adj[v * NBK]);
#pragma unroll
        for (int j = 0; j < 5; j++) { int2 p = arow[j]; nb[2 * j] = p.x; nb[2 * j + 1] = p.y; }
    } else {
#pragma unroll
        for (int n = 0; n < NBK; n++) nb[n] = 0;
    }
    int cnt = 0;
#pragma unroll
    for (int n = 0; n < NBK; n++) cnt += (nb[n] != 0) ? 1 : 0;
    const float rec = cnt ? (1.0f / (float)cnt) : 0.0f;
    layer0_body<false>(tid, g, t, act, b, v, vv, nb, rec,
        x, Win, u0, W, bvec, cvec, unx, hux_out, s_w);
}

template<int CIN, int COUT, bool LAST, int RSI, int RSO>
__global__ __launch_bounds__(512, 4) void nlayer_kernel(
    const float* __restrict__ hux_in, const int* __restrict__ adj,
    const float* __restrict__ W, const float* __restrict__ bvec,
    const float* __restrict__ cvec, const float* __restrict__ unx,
    float* __restrict__ hux_out, float* __restrict__ dout)
{
    constexpr int COUTP = (COUT == 32) ? 36 : ((COUT == 16) ? 20 : 4);
    __shared__ __align__(16) float s_w[KK * CIN * COUTP];
    __shared__ __align__(16) float s_q[32][NBK][12];
    const int tid = threadIdx.x;
    const int g = tid >> 4;
    const int t = tid & 15;
    const int vv = blockIdx.x * 32 + g;
    const bool act = vv < TOT;
    int b = 0, v = 0;
    if (act) { b = vv / Vv; v = vv - b * Vv; }
    int nb[NBK];
    if (act) {
        const int2* arow = reinterpret_cast<const int2*>(&adj[v * NBK]);
#pragma unroll
        for (int j = 0; j < 5; j++) { int2 p = arow[j]; nb[2 * j] = p.x; nb[2 * j + 1] = p.y; }
    } else {
#pragma unroll
        for (int n = 0; n < NBK; n++) nb[n] = 0;
    }
    int cnt = 0;
#pragma unroll
    for (int n = 0; n < NBK; n++) cnt += (nb[n] != 0) ? 1 : 0;
    const float rec = cnt ? (1.0f / (float)cnt) : 0.0f;
    nlayer_body<CIN, COUT, LAST, RSI, RSO, false, 512>(tid, g, t, act, b, v, vv, nb, rec,
        hux_in, W, bvec, cvec, unx, hux_out, dout, s_w,
        reinterpret_cast<float(*)[NBK][12]>(s_q));
}

// ---------------------------------------------------------------------------
extern "C" void kernel_launch(void* const* d_in, const int* in_sizes, int n_in,
                              void* d_out, int out_size, void* d_ws, size_t ws_size,
                              hipStream_t stream)
{
    const float* x    = (const float*)d_in[0];
    const int*   adj  = (const int*)  d_in[1];
    const float* Win  = (const float*)d_in[2];
    const float* Wout = (const float*)d_in[3];
    const float *W[6], *bb[6], *uu[6], *cc[6];
    for (int i = 0; i < 6; i++) {
        W[i]  = (const float*)d_in[4 + 4 * i];
        bb[i] = (const float*)d_in[5 + 4 * i];
        uu[i] = (const float*)d_in[6 + 4 * i];
        cc[i] = (const float*)d_in[7 + 4 * i];
    }
    float* out = (float*)d_out;

    // Workspace: [Bar x5 (16KB) | B1,B2 (RS32) | B3 (RS48) | B4,B5 (RS32)]
    char*  wsb  = (char*)d_ws;
    Bar*   bars = (Bar*)wsb;
    float* p    = (float*)(wsb + 16384);
    float* B1 = p; p += (size_t)TOT * 32;
    float* B2 = p; p += (size_t)TOT * 32;
    float* B3 = p; p += (size_t)TOT * 48;
    float* B4 = p; p += (size_t)TOT * 32;
    float* B5 = p; p += (size_t)TOT * 32;

    // co-residency check (host-side queries; capture-safe)
    int dev = 0, ncu = 0, maxb = 0;
    (void)hipGetDevice(&dev);
    (void)hipDeviceGetAttribute(&ncu, hipDeviceAttributeMultiprocessorCount, dev);
    hipError_t oe = hipOccupancyMaxActiveBlocksPerMultiprocessor(&maxb, fused_kernel, 256, 0);
    const bool use_fused = (oe == hipSuccess) && (ncu > 0) &&
                           ((long)maxb * ncu >= NBLK_F);

    if (use_fused) {
        (void)hipMemsetAsync(d_ws, 0, sizeof(Bar) * NBARS, stream);
        KArgs A;
        A.x = x; A.adj = adj; A.Win = Win; A.Wout = Wout;
        for (int i = 0; i < 6; i++) { A.W[i] = W[i]; A.bv[i] = bb[i]; A.uv[i] = uu[i]; A.cv[i] = cc[i]; }
        A.bars = bars;
        A.B1 = B1; A.B2 = B2; A.B3 = B3; A.B4 = B4; A.B5 = B5;
        A.out = out;
        fused_kernel<<<NBLK_F, 256, 0, stream>>>(A);
        return;
    }

    // fallback: verified r12 six-dispatch path
    const int nb1 = (TOT + 15) / 16;
    const int nb2 = (TOT + 31) / 32;
    enc_l0_kernel<<<nb1, 256, 0, stream>>>(x, adj, Win, uu[0], W[0], bb[0], cc[0],
                                           uu[1], B1);
    nlayer_kernel<16, 16, false, 32, 32><<<nb2, 512, 0, stream>>>(B1, adj, W[1], bb[1], cc[1], uu[2], B2, nullptr);
    nlayer_kernel<16, 32, false, 32, 48><<<nb2, 512, 0, stream>>>(B2, adj, W[2], bb[2], cc[2], uu[3], B3, nullptr);
    nlayer_kernel<32, 16, false, 48, 32><<<nb2, 512, 0, stream>>>(B3, adj, W[3], bb[3], cc[3], uu[4], B4, nullptr);
    nlayer_kernel<16, 16, false, 32, 32><<<nb2, 512, 0, stream>>>(B4, adj, W[4], bb[4], cc[4], uu[5], B5, nullptr);
    nlayer_kernel<16, 3, true, 32, 32><<<nb2, 512, 0, stream>>>(B5, adj, W[5], bb[5], cc[5], Wout, nullptr, out);
}

// Round 14
// 76.671 us; speedup vs baseline: 1.4489x; 1.4489x over previous
//
#include <hip/hip_runtime.h>

#define NBK 10
#define KK  9

constexpr int Bv  = 4;
constexpr int Vv  = 5023;
constexpr int TOT = Bv * Vv;   // 20092

// interleaved row strides: RS32: h 0..15, ux 16..24;  RS48: h 0..31, ux 32..40

// ---------------------------------------------------------------------------
// 16-lane merge-tree reduce (verified r3-r12).
// ---------------------------------------------------------------------------
__device__ __forceinline__ float merge16(float* a, int t)
{
#pragma unroll
    for (int j = 0; j < 8; j++) {
        float send = (t & 8) ? a[j] : a[j + 8];
        float keep = (t & 8) ? a[j + 8] : a[j];
        a[j] = keep + __shfl_xor(send, 8, 16);
    }
#pragma unroll
    for (int j = 0; j < 4; j++) {
        float send = (t & 4) ? a[j] : a[j + 4];
        float keep = (t & 4) ? a[j + 4] : a[j];
        a[j] = keep + __shfl_xor(send, 4, 16);
    }
#pragma unroll
    for (int j = 0; j < 2; j++) {
        float send = (t & 2) ? a[j] : a[j + 2];
        float keep = (t & 2) ? a[j + 2] : a[j];
        a[j] = keep + __shfl_xor(send, 2, 16);
    }
    {
        float send = (t & 1) ? a[0] : a[1];
        float keep = (t & 1) ? a[1] : a[0];
        a[0] = keep + __shfl_xor(send, 1, 16);
    }
    return a[0];
}

// ---------------------------------------------------------------------------
// K1: encoder+layer0 (verified r10). Stage-first, one barrier.
// ---------------------------------------------------------------------------
__global__ __launch_bounds__(256, 4) void enc_l0_kernel(
    const float* __restrict__ x, const int* __restrict__ adj,
    const float* __restrict__ Win, const float* __restrict__ u0,
    const float* __restrict__ W, const float* __restrict__ bvec,
    const float* __restrict__ cvec, const float* __restrict__ unx,
    float* __restrict__ hux_out)
{
    constexpr int COUTP = 20;
    __shared__ __align__(16) float s_w[KK * 16 * COUTP];

    const int tid = threadIdx.x;

    {
        constexpr int NF4 = 16 * KK * 16 / 4;   // 576
        constexpr int KC4 = KK * 16 / 4;        // 36
        const float4* W4 = reinterpret_cast<const float4*>(W);
        for (int i = tid; i < NF4; i += 256) {
            const int c   = i / KC4;
            const int rem = i - c * KC4;
            const int k   = rem >> 2;
            const int o4  = rem & 3;
            *reinterpret_cast<float4*>(&s_w[(k * 16 + c) * COUTP + o4 * 4]) = W4[i];
        }
    }
    __syncthreads();

    const int g = tid >> 4;
    const int t = tid & 15;
    const int vv = blockIdx.x * 16 + g;
    if (vv >= TOT) return;
    const int b = vv / Vv;
    const int v = vv - b * Vv;
    const float* xB = x + (size_t)b * Vv * 3;

    int nb[NBK];
    const int2* arow = reinterpret_cast<const int2*>(&adj[v * NBK]);
#pragma unroll
    for (int j = 0; j < 5; j++) { int2 p = arow[j]; nb[2 * j] = p.x; nb[2 * j + 1] = p.y; }
    int cnt = 0;
#pragma unroll
    for (int n = 0; n < NBK; n++) cnt += (nb[n] != 0) ? 1 : 0;
    const float rec = cnt ? (1.0f / (float)cnt) : 0.0f;

    const float w0 = Win[t], w1 = Win[16 + t], w2 = Win[32 + t];
    float hn0[NBK];
#pragma unroll
    for (int n = 0; n < NBK; n++) {
        const int a = nb[n];
        float x0 = 0.f, x1 = 0.f, x2 = 0.f;
        if (a) {
            const float* xr = &xB[(size_t)(a - 1) * 3];
            x0 = xr[0]; x1 = xr[1]; x2 = xr[2];
        }
        hn0[n] = fmaxf(x0 * w0 + x1 * w1 + x2 * w2, 0.0f);
    }

    float q[KK] = {};
    if (t < NBK) {
        const float* xo = &xB[(size_t)v * 3];
        const float xo0 = xo[0], xo1 = xo[1], xo2 = xo[2];
        const int a = nb[t];
        float xn0 = 0.f, xn1 = 0.f, xn2 = 0.f;
        if (a) {
            const float* xr = &xB[(size_t)(a - 1) * 3];
            xn0 = xr[0]; xn1 = xr[1]; xn2 = xr[2];
        }
        float hs[16];
#pragma unroll
        for (int c = 0; c < 16; c++) {
            const float ho = fmaxf(xo0 * Win[c] + xo1 * Win[16 + c] + xo2 * Win[32 + c], 0.0f);
            const float hn = fmaxf(xn0 * Win[c] + xn1 * Win[16 + c] + xn2 * Win[32 + c], 0.0f);
            hs[c] = ho + hn;
        }
        float lg[KK];
#pragma unroll
        for (int k = 0; k < KK; k++) {
            float s = cvec[k];
#pragma unroll
            for (int c = 0; c < 16; c++) s = fmaf(hs[c], u0[c * KK + k], s);
            lg[k] = s;
        }
        float m = lg[0];
#pragma unroll
        for (int k = 1; k < KK; k++) m = fmaxf(m, lg[k]);
        float sum = 0.0f;
#pragma unroll
        for (int k = 0; k < KK; k++) { q[k] = __expf(lg[k] - m); sum += q[k]; }
        const float r = 1.0f / sum;
#pragma unroll
        for (int k = 0; k < KK; k++) q[k] *= r;
    }

    float g0[KK];
#pragma unroll
    for (int k = 0; k < KK; k++) g0[k] = 0.0f;
#pragma unroll
    for (int n = 0; n < NBK; n++) {
#pragma unroll
        for (int k = 0; k < KK; k++) {
            const float qnk = __shfl(q[k], n, 16);
            g0[k] = fmaf(qnk, hn0[n], g0[k]);
        }
    }

    float acc[16] = {};
#pragma unroll
    for (int k = 0; k < KK; k++) {
        const float g0k = g0[k];
        const float* wr = &s_w[(k * 16 + t) * COUTP];
#pragma unroll
        for (int o4 = 0; o4 < 4; o4++) {
            const float4 w = *reinterpret_cast<const float4*>(&wr[4 * o4]);
            acc[4 * o4 + 0] = fmaf(g0k, w.x, acc[4 * o4 + 0]);
            acc[4 * o4 + 1] = fmaf(g0k, w.y, acc[4 * o4 + 1]);
            acc[4 * o4 + 2] = fmaf(g0k, w.z, acc[4 * o4 + 2]);
            acc[4 * o4 + 3] = fmaf(g0k, w.w, acc[4 * o4 + 3]);
        }
    }

    const float o0 = merge16(acc, t);
    const float h0v = fmaxf(fmaf(o0, rec, bvec[t]), 0.0f);
    float* row = &hux_out[(size_t)vv * 32];
    row[t] = h0v;

    float uxv = 0.0f;
#pragma unroll
    for (int o = 0; o < 16; o++) {
        const float hb = __shfl(h0v, o, 16);
        if (t < KK) uxv = fmaf(hb, unx[o * KK + t], uxv);
    }
    if (t < KK) row[16 + t] = uxv;
}

// ---------------------------------------------------------------------------
// K2..K6: one-barrier NLayer (verified r10), early gathers, interleaved rows.
// ---------------------------------------------------------------------------
template<int CIN, int COUT, bool LAST, int RSI, int RSO>
__global__ __launch_bounds__(256) void nlayer_kernel(
    const float* __restrict__ hux_in,  // rows RSI: h at 0, ux at CIN
    const int*   __restrict__ adj,     // [Vv,NBK]
    const float* __restrict__ W,       // [CIN,KK,COUT]
    const float* __restrict__ bvec,    // [COUT]
    const float* __restrict__ cvec,    // [KK]
    const float* __restrict__ unx,     // [COUT,KK] (or Wout [3,3] if LAST)
    float* __restrict__ hux_out,       // rows RSO
    float* __restrict__ dout)          // [TOT,3] if LAST
{
    constexpr int COUTP = (COUT == 32) ? 36 : ((COUT == 16) ? 20 : 4);

    __shared__ __align__(16) float s_w[KK * CIN * COUTP];
    __shared__ __align__(16) float s_q[16][NBK][12];

    const int tid = threadIdx.x;
    const int g = tid >> 4;
    const int t = tid & 15;
    const int vv = blockIdx.x * 16 + g;
    const bool act = vv < TOT;
    int b = 0, v = 0;
    if (act) { b = vv / Vv; v = vv - b * Vv; }
    const float* inB = hux_in + (size_t)b * Vv * RSI;

    // --- early: adjacency row ---
    int nb[NBK];
    if (act) {
        const int2* arow = reinterpret_cast<const int2*>(&adj[v * NBK]);
#pragma unroll
        for (int j = 0; j < 5; j++) { int2 p = arow[j]; nb[2 * j] = p.x; nb[2 * j + 1] = p.y; }
    } else {
#pragma unroll
        for (int n = 0; n < NBK; n++) nb[n] = 0;
    }
    int cnt = 0;
#pragma unroll
    for (int n = 0; n < NBK; n++) cnt += (nb[n] != 0) ? 1 : 0;
    const float rec = cnt ? (1.0f / (float)cnt) : 0.0f;

    // --- early: register gather of neighbor h (owned channel(s)) ---
    float hn0[NBK], hn1[NBK];
#pragma unroll
    for (int n = 0; n < NBK; n++) {
        const int a = nb[n];
        const float* r = &inB[(size_t)(a - 1) * RSI];
        hn0[n] = a ? r[t] : 0.0f;
        if constexpr (CIN == 32) hn1[n] = a ? r[t + 16] : 0.0f;
        else                     hn1[n] = 0.0f;
    }

    // --- early: own + neighbor ux (lane t<10), same rows as h gathers ---
    float4 s0 = make_float4(0.f, 0.f, 0.f, 0.f), s1 = s0, n0 = s0, n1 = s0;
    float  s8 = 0.f, n8 = 0.f;
    if (t < NBK) {
        const float* su = &inB[(size_t)v * RSI + CIN];
        s0 = *reinterpret_cast<const float4*>(su);
        s1 = *reinterpret_cast<const float4*>(su + 4);
        s8 = su[8];
        const int a = nb[t];
        if (a) {
            const float* nu = &inB[(size_t)(a - 1) * RSI + CIN];
            n0 = *reinterpret_cast<const float4*>(nu);
            n1 = *reinterpret_cast<const float4*>(nu + 4);
            n8 = nu[8];
        }
    }

    // --- stage W -> LDS [k][c][o] padded (overlaps with gathers in flight) ---
    if constexpr (!LAST) {
        constexpr int NF4 = CIN * KK * COUT / 4;
        constexpr int KC4 = KK * COUT / 4;
        constexpr int C4  = COUT / 4;
        const float4* W4 = reinterpret_cast<const float4*>(W);
        for (int i = tid; i < NF4; i += 256) {
            const int c   = i / KC4;
            const int rem = i - c * KC4;
            const int k   = rem / C4;
            const int o4  = rem - k * C4;
            *reinterpret_cast<float4*>(&s_w[(k * CIN + c) * COUTP + o4 * 4]) = W4[i];
        }
    } else {
        for (int i = tid; i < CIN * KK * 3; i += 256) {
            const int c   = i / (KK * 3);
            const int rem = i - c * (KK * 3);
            const int k   = rem / 3;
            const int o   = rem - k * 3;
            s_w[(k * CIN + c) * COUTP + o] = W[i];
        }
    }
    __syncthreads();
    if (!act) return;

    // --- softmax over k (lane t<10), in registers -> wave-private s_q ---
    if (t < NBK) {
        float lg[KK] = { s0.x + n0.x + cvec[0], s0.y + n0.y + cvec[1],
                         s0.z + n0.z + cvec[2], s0.w + n0.w + cvec[3],
                         s1.x + n1.x + cvec[4], s1.y + n1.y + cvec[5],
                         s1.z + n1.z + cvec[6], s1.w + n1.w + cvec[7],
                         s8 + n8 + cvec[8] };
        float m = lg[0];
#pragma unroll
        for (int k = 1; k < KK; k++) m = fmaxf(m, lg[k]);
        float e[KK], sum = 0.0f;
#pragma unroll
        for (int k = 0; k < KK; k++) { e[k] = __expf(lg[k] - m); sum += e[k]; }
        const float r = 1.0f / sum;
        *reinterpret_cast<float4*>(&s_q[g][t][0]) =
            make_float4(e[0] * r, e[1] * r, e[2] * r, e[3] * r);
        *reinterpret_cast<float4*>(&s_q[g][t][4]) =
            make_float4(e[4] * r, e[5] * r, e[6] * r, e[7] * r);
        s_q[g][t][8] = e[8] * r;
    }
    // wave-local LDS RAW: lgkmcnt orders write->read within the wave.

    // --- G-phase ---
    float g0[KK], g1[KK];
#pragma unroll
    for (int k = 0; k < KK; k++) { g0[k] = 0.0f; g1[k] = 0.0f; }
#pragma unroll
    for (int n = 0; n < NBK; n++) {
        const float4 qa = *reinterpret_cast<const float4*>(&s_q[g][n][0]);
        const float4 qb = *reinterpret_cast<const float4*>(&s_q[g][n][4]);
        const float  q8 = s_q[g][n][8];
        const float h0 = hn0[n];
        g0[0] = fmaf(qa.x, h0, g0[0]); g0[1] = fmaf(qa.y, h0, g0[1]);
        g0[2] = fmaf(qa.z, h0, g0[2]); g0[3] = fmaf(qa.w, h0, g0[3]);
        g0[4] = fmaf(qb.x, h0, g0[4]); g0[5] = fmaf(qb.y, h0, g0[5]);
        g0[6] = fmaf(qb.z, h0, g0[6]); g0[7] = fmaf(qb.w, h0, g0[7]);
        g0[8] = fmaf(q8,   h0, g0[8]);
        if constexpr (CIN == 32) {
            const float h1 = hn1[n];
            g1[0] = fmaf(qa.x, h1, g1[0]); g1[1] = fmaf(qa.y, h1, g1[1]);
            g1[2] = fmaf(qa.z, h1, g1[2]); g1[3] = fmaf(qa.w, h1, g1[3]);
            g1[4] = fmaf(qb.x, h1, g1[4]); g1[5] = fmaf(qb.y, h1, g1[5]);
            g1[6] = fmaf(qb.z, h1, g1[6]); g1[7] = fmaf(qb.w, h1, g1[7]);
            g1[8] = fmaf(q8,   h1, g1[8]);
        }
    }

    if constexpr (!LAST) {
        // --- E-phase: ds_read_b128 rows of s_w[k][c=t][*] ---
        float acc[COUT] = {};
#pragma unroll
        for (int k = 0; k < KK; k++) {
            const float g0k = g0[k];
            const float* wr = &s_w[(k * CIN + t) * COUTP];
#pragma unroll
            for (int o4 = 0; o4 < COUT / 4; o4++) {
                const float4 w = *reinterpret_cast<const float4*>(&wr[4 * o4]);
                acc[4 * o4 + 0] = fmaf(g0k, w.x, acc[4 * o4 + 0]);
                acc[4 * o4 + 1] = fmaf(g0k, w.y, acc[4 * o4 + 1]);
                acc[4 * o4 + 2] = fmaf(g0k, w.z, acc[4 * o4 + 2]);
                acc[4 * o4 + 3] = fmaf(g0k, w.w, acc[4 * o4 + 3]);
            }
            if constexpr (CIN == 32) {
                const float g1k = g1[k];
                const float* wr2 = &s_w[(k * CIN + t + 16) * COUTP];
#pragma unroll
                for (int o4 = 0; o4 < COUT / 4; o4++) {
                    const float4 w = *reinterpret_cast<const float4*>(&wr2[4 * o4]);
                    acc[4 * o4 + 0] = fmaf(g1k, w.x, acc[4 * o4 + 0]);
                    acc[4 * o4 + 1] = fmaf(g1k, w.y, acc[4 * o4 + 1]);
                    acc[4 * o4 + 2] = fmaf(g1k, w.z, acc[4 * o4 + 2]);
                    acc[4 * o4 + 3] = fmaf(g1k, w.w, acc[4 * o4 + 3]);
                }
            }
        }

        const float o0 = merge16(acc, t);
        const float h0v = fmaxf(fmaf(o0, rec, bvec[t]), 0.0f);
        float* row = &hux_out[(size_t)vv * RSO];
        row[t] = h0v;
        float h1v = 0.0f;
        if constexpr (COUT == 32) {
            const float o1 = merge16(acc + 16, t);
            h1v = fmaxf(fmaf(o1, rec, bvec[t + 16]), 0.0f);
            row[16 + t] = h1v;
        }

        // --- fused ux for next layer (shuffle broadcast) ---
        float uxv = 0.0f;
#pragma unroll
        for (int o = 0; o < 16; o++) {
            const float hb = __shfl(h0v, o, 16);
            if (t < KK) uxv = fmaf(hb, unx[o * KK + t], uxv);
        }
        if constexpr (COUT == 32) {
#pragma unroll
            for (int o = 0; o < 16; o++) {
                const float hb = __shfl(h1v, o, 16);
                if (t < KK) uxv = fmaf(hb, unx[(o + 16) * KK + t], uxv);
            }
        }
        if (t < KK) row[COUT + t] = uxv;
    } else {
        // COUT == 3: fused decoder
        float acc[3] = {};
#pragma unroll
        for (int k = 0; k < KK; k++) {
            const float4 w = *reinterpret_cast<const float4*>(&s_w[(k * CIN + t) * COUTP]);
            acc[0] = fmaf(g0[k], w.x, acc[0]);
            acc[1] = fmaf(g0[k], w.y, acc[1]);
            acc[2] = fmaf(g0[k], w.z, acc[2]);
        }
#pragma unroll
        for (int o = 0; o < 3; o++) {
            acc[o] += __shfl_xor(acc[o], 1, 16);
            acc[o] += __shfl_xor(acc[o], 2, 16);
            acc[o] += __shfl_xor(acc[o], 4, 16);
            acc[o] += __shfl_xor(acc[o], 8, 16);
        }
        float hnew[3];
#pragma unroll
        for (int o = 0; o < 3; o++)
            hnew[o] = fmaxf(fmaf(acc[o], rec, bvec[o]), 0.0f);
        if (t < 3) {
            float s = 0.0f;
#pragma unroll
            for (int j = 0; j < 3; j++)
                s = fmaf(hnew[j], unx[j * 3 + t], s);
            dout[(size_t)vv * 3 + t] = s;
        }
    }
}

// ---------------------------------------------------------------------------
extern "C" void kernel_launch(void* const* d_in, const int* in_sizes, int n_in,
                              void* d_out, int out_size, void* d_ws, size_t ws_size,
                              hipStream_t stream)
{
    const float* x    = (const float*)d_in[0];
    const int*   adj  = (const int*)  d_in[1];
    const float* Win  = (const float*)d_in[2];
    const float* Wout = (const float*)d_in[3];
    const float *W[6], *bb[6], *uu[6], *cc[6];
    for (int i = 0; i < 6; i++) {
        W[i]  = (const float*)d_in[4 + 4 * i];
        bb[i] = (const float*)d_in[5 + 4 * i];
        uu[i] = (const float*)d_in[6 + 4 * i];
        cc[i] = (const float*)d_in[7 + 4 * i];
    }
    float* out = (float*)d_out;

    // interleaved h|ux buffers: B1,B2 (RS32), B3 (RS48), B4,B5 (RS32)
    float* p  = (float*)d_ws;
    float* B1 = p; p += (size_t)TOT * 32;
    float* B2 = p; p += (size_t)TOT * 32;
    float* B3 = p; p += (size_t)TOT * 48;
    float* B4 = p; p += (size_t)TOT * 32;
    float* B5 = p; p += (size_t)TOT * 32;

    const int nb = (TOT + 15) / 16;   // 1256 blocks, 16 vertices/block

    enc_l0_kernel<<<nb, 256, 0, stream>>>(x, adj, Win, uu[0], W[0], bb[0], cc[0],
                                          uu[1], B1);
    nlayer_kernel<16, 16, false, 32, 32><<<nb, 256, 0, stream>>>(B1, adj, W[1], bb[1], cc[1], uu[2], B2, nullptr);
    nlayer_kernel<16, 32, false, 32, 48><<<nb, 256, 0, stream>>>(B2, adj, W[2], bb[2], cc[2], uu[3], B3, nullptr);
    nlayer_kernel<32, 16, false, 48, 32><<<nb, 256, 0, stream>>>(B3, adj, W[3], bb[3], cc[3], uu[4], B4, nullptr);
    nlayer_kernel<16, 16, false, 32, 32><<<nb, 256, 0, stream>>>(B4, adj, W[4], bb[4], cc[4], uu[5], B5, nullptr);
    nlayer_kernel<16, 3, true, 32, 32><<<nb, 256, 0, stream>>>(B5, adj, W[5], bb[5], cc[5], Wout, nullptr, out);
}